// Round 3
// baseline (2198.786 us; speedup 1.0000x reference)
//
#include <hip/hip_runtime.h>
#include <hip/hip_bf16.h>
#include <stdint.h>

// Problem constants
#define T_   128
#define B_   32
#define V_   50257
#define E_   512
#define H_   512
#define L_   2
#define G4   2048          // 4*H
#define KC   1024          // E + H (concat [x;h] K dim)
#define VPAD 50304         // 393 * 128 (decoder N padded)

typedef __attribute__((ext_vector_type(8))) short bf16x8;
typedef __attribute__((ext_vector_type(4))) float f32x4;
typedef unsigned short u16;
typedef unsigned int   u32;

// ---- workspace layout (bytes) ----
constexpr size_t OFF_CNT  = 0;                                    // 2 ints
constexpr size_t OFF_BSUM = 256;                                  // L*4H f32 = 16KB
constexpr size_t OFF_X0   = OFF_BSUM + (size_t)L_*G4*4;           // T*B*E bf16 = 4MB
constexpr size_t OFF_HS1  = OFF_X0  + (size_t)T_*B_*E_*2;         // (T+1)*B*H bf16
constexpr size_t OFF_HS2  = OFF_HS1 + (size_t)(T_+1)*B_*H_*2;
constexpr size_t OFF_WCAT = OFF_HS2 + (size_t)(T_+1)*B_*H_*2;     // L*4H*KC bf16 = 8MB
constexpr size_t OFF_DECW = OFF_WCAT + (size_t)L_*G4*KC*2;        // VPAD*H bf16 = 51.5MB
// total ~69.2 MB

__device__ inline u16 f2bf(float f) {
  u32 u = __float_as_uint(f);
  u = u + 0x7fffu + ((u >> 16) & 1u);   // RNE
  return (u16)(u >> 16);
}

__device__ inline void cvt8(const float* s, u16* d) {
  float4 f0 = *(const float4*)s;
  float4 f1 = *(const float4*)(s + 4);
  u32 p0 = (u32)f2bf(f0.x) | ((u32)f2bf(f0.y) << 16);
  u32 p1 = (u32)f2bf(f0.z) | ((u32)f2bf(f0.w) << 16);
  u32 p2 = (u32)f2bf(f1.x) | ((u32)f2bf(f1.y) << 16);
  u32 p3 = (u32)f2bf(f1.z) | ((u32)f2bf(f1.w) << 16);
  *(uint4*)d = make_uint4(p0, p1, p2, p3);
}

// ---- prep: zero counters, bias sum, h0 -> bf16 slot0 ----
__global__ void k_prep(const float* h0, const float* bih, const float* bhh, char* ws) {
  int idx = blockIdx.x * 256 + threadIdx.x;  // grid covers 32768
  int* cnt = (int*)(ws + OFF_CNT);
  float* bsum = (float*)(ws + OFF_BSUM);
  u16* hs1 = (u16*)(ws + OFF_HS1);
  u16* hs2 = (u16*)(ws + OFF_HS2);
  if (idx < 2) cnt[idx] = 0;
  if (idx < L_ * G4) bsum[idx] = bih[idx] + bhh[idx];
  if (idx < L_ * B_ * H_) {
    int l = idx / (B_ * H_);
    int r = idx % (B_ * H_);
    u16 v = f2bf(h0[idx]);
    if (l == 0) hs1[r] = v; else hs2[r] = v;
  }
}

// ---- embedding lookup -> bf16 x0 ----
__global__ void k_embed(const int* tok, const float* embW, char* ws) {
  int idx = blockIdx.x * 256 + threadIdx.x;      // T*B*64 = 262144
  int tb = idx >> 6, e8 = (idx & 63) * 8;
  int t = tok[tb];
  const float* s = embW + (size_t)t * E_ + e8;
  u16* d = (u16*)(ws + OFF_X0) + (size_t)tb * E_ + e8;
  cvt8(s, d);
}

// ---- concat [Wih | Whh] -> bf16 Wcat [L][4H][KC] ----
__global__ void k_wcat(const float* wih, const float* whh, char* ws) {
  int idx = blockIdx.x * 256 + threadIdx.x;      // L*4H*128 = 524288
  int row = idx >> 7;                            // l*2048 + n
  int k = (idx & 127) * 8;
  const float* s = (k < E_) ? (wih + (size_t)row * E_ + k)
                            : (whh + (size_t)row * H_ + (k - E_));
  u16* d = (u16*)(ws + OFF_WCAT) + (size_t)row * KC + k;
  cvt8(s, d);
}

// ---- dec_W -> bf16, padded with zero rows to VPAD ----
__global__ void k_decw(const float* decw, char* ws) {
  int idx = blockIdx.x * 256 + threadIdx.x;      // VPAD*64 = 3219456
  int n = idx >> 6, k = (idx & 63) * 8;
  u16* d = (u16*)(ws + OFF_DECW) + (size_t)n * H_ + k;
  if (n < V_) {
    cvt8(decw + (size_t)n * H_ + k, d);
  } else {
    *(uint4*)d = make_uint4(0, 0, 0, 0);
  }
}

// ---- persistent LSTM: 64 WGs (32 per layer), weights in VGPRs ----
// WG (l, wgi): owns h-cols [wgi*16, wgi*16+16). 4 waves split K=1024 (x||h).
__global__ void __launch_bounds__(256, 1) k_lstm(const float* c0, char* ws, float* outHC) {
  __shared__ float gpart[4][32][64];   // per-wave partial gates [batch][4gates x 16cols]
  __shared__ float cst[32][16];        // cell state for owned cols

  const int tid = threadIdx.x;
  const int w = tid >> 6, lane = tid & 63;
  const int wg = blockIdx.x;
  const int l = wg >> 5, wgi = wg & 31;
  const int hb = wgi * 16;

  int* cnt = (int*)(ws + OFF_CNT);
  const u16* x0 = (const u16*)(ws + OFF_X0);
  u16* hs1 = (u16*)(ws + OFF_HS1);
  u16* hs2 = (u16*)(ws + OFF_HS2);
  u16* hsl = l ? hs2 : hs1;
  const u16* Wl = (const u16*)(ws + OFF_WCAT) + (size_t)l * G4 * KC;
  const float* bsum = (const float*)(ws + OFF_BSUM) + l * G4;

  const int r16 = lane & 15;
  const int q8 = (lane >> 4) * 8;

  // Preload B fragments: 4 gate-blocks x 8 k-steps, this wave's K range [w*256, w*256+256)
  bf16x8 bfr[4][8];
  #pragma unroll
  for (int ng = 0; ng < 4; ++ng)
    #pragma unroll
    for (int ks = 0; ks < 8; ++ks)
      bfr[ng][ks] = *(const bf16x8*)(Wl + (size_t)(ng * 512 + hb + r16) * KC
                                        + (w * 256 + ks * 32 + q8));

  const int koff = (w & 1) * 256;  // k-offset within the wave's source (x or h)

  for (int t = 0; t < T_; ++t) {
    // ---- wait for inputs ----
    if (tid == 0) {
      if (l == 0) {
        if (t > 0)
          while (__hip_atomic_load(&cnt[0], __ATOMIC_ACQUIRE, __HIP_MEMORY_SCOPE_AGENT) < 32 * t)
            __builtin_amdgcn_s_sleep(1);
      } else {
        while (__hip_atomic_load(&cnt[0], __ATOMIC_ACQUIRE, __HIP_MEMORY_SCOPE_AGENT) < 32 * (t + 1))
          __builtin_amdgcn_s_sleep(1);
        if (t > 0)
          while (__hip_atomic_load(&cnt[1], __ATOMIC_ACQUIRE, __HIP_MEMORY_SCOPE_AGENT) < 32 * t)
            __builtin_amdgcn_s_sleep(1);
      }
    }
    __syncthreads();

    // ---- A source: waves 0,1 read x-part; waves 2,3 read h_{t-1} ----
    const u16* Asrc;
    if (w < 2) Asrc = (l == 0) ? (x0 + (size_t)t * (B_ * E_)) : (hs1 + (size_t)(t + 1) * (B_ * H_));
    else       Asrc = hsl + (size_t)t * (B_ * H_);
    const u16* Ar = Asrc + (size_t)r16 * 512 + koff + q8;

    f32x4 zero = {0.f, 0.f, 0.f, 0.f};
    f32x4 acc[2][4];
    #pragma unroll
    for (int m = 0; m < 2; ++m)
      #pragma unroll
      for (int ng = 0; ng < 4; ++ng) acc[m][ng] = zero;

    #pragma unroll
    for (int ks = 0; ks < 8; ++ks) {
      bf16x8 a0 = *(const bf16x8*)(Ar + ks * 32);
      bf16x8 a1 = *(const bf16x8*)(Ar + 16 * 512 + ks * 32);
      #pragma unroll
      for (int ng = 0; ng < 4; ++ng) {
        acc[0][ng] = __builtin_amdgcn_mfma_f32_16x16x32_bf16(a0, bfr[ng][ks], acc[0][ng], 0, 0, 0);
        acc[1][ng] = __builtin_amdgcn_mfma_f32_16x16x32_bf16(a1, bfr[ng][ks], acc[1][ng], 0, 0, 0);
      }
    }

    // ---- partials to LDS ----
    #pragma unroll
    for (int m = 0; m < 2; ++m)
      #pragma unroll
      for (int ng = 0; ng < 4; ++ng)
        #pragma unroll
        for (int r = 0; r < 4; ++r)
          gpart[w][m * 16 + (lane >> 4) * 4 + r][ng * 16 + r16] = acc[m][ng][r];
    __syncthreads();

    // ---- reduce + gates + cell update: thread -> 2 adjacent (b,hc) units ----
    {
      int b = tid >> 3;
      int hc0 = (tid & 7) * 2;
      float hv[2], cv[2];
      #pragma unroll
      for (int u = 0; u < 2; ++u) {
        int hc = hc0 + u;
        float g0 = bsum[0 * 512 + hb + hc];
        float g1 = bsum[1 * 512 + hb + hc];
        float g2 = bsum[2 * 512 + hb + hc];
        float g3 = bsum[3 * 512 + hb + hc];
        #pragma unroll
        for (int ww = 0; ww < 4; ++ww) {
          g0 += gpart[ww][b][ 0 + hc];
          g1 += gpart[ww][b][16 + hc];
          g2 += gpart[ww][b][32 + hc];
          g3 += gpart[ww][b][48 + hc];
        }
        float ig = 1.f / (1.f + __expf(-g0));
        float fg = 1.f / (1.f + __expf(-g1));
        float gg = tanhf(g2);
        float og = 1.f / (1.f + __expf(-g3));
        float cprev = (t == 0) ? c0[(size_t)l * B_ * H_ + b * H_ + hb + hc] : cst[b][hc];
        float cc = fg * cprev + ig * gg;
        cst[b][hc] = cc;
        hv[u] = og * tanhf(cc);
        cv[u] = cc;
      }
      // publish h (write-through to coherent point: agent-scope relaxed store)
      u32 pk = (u32)f2bf(hv[0]) | ((u32)f2bf(hv[1]) << 16);
      u32* hdst = (u32*)(hsl + (size_t)(t + 1) * (B_ * H_) + b * H_ + hb + hc0);
      __hip_atomic_store(hdst, pk, __ATOMIC_RELAXED, __HIP_MEMORY_SCOPE_AGENT);
      if (t == T_ - 1) {
        size_t ob = (size_t)l * B_ * H_ + (size_t)b * H_ + hb + hc0;
        outHC[ob]     = hv[0];
        outHC[ob + 1] = hv[1];
        outHC[(size_t)L_ * B_ * H_ + ob]     = cv[0];
        outHC[(size_t)L_ * B_ * H_ + ob + 1] = cv[1];
      }
    }
    __syncthreads();  // all waves' LDS writes + h stores drained (waitcnt before barrier)
    if (tid == 0) {
      __threadfence();  // agent fence: make h visible device-wide (cross-XCD)
      __hip_atomic_fetch_add(&cnt[l], 1, __ATOMIC_RELEASE, __HIP_MEMORY_SCOPE_AGENT);
    }
  }
}

// ---- decoder GEMM: [4096,512]bf16 @ [VPAD,512]bf16^T -> fp32 logits + bias ----
// BM=BN=128, BK=64, 4 waves 2x2, each 64x64. global_load_lds staging, linear LDS.
__global__ void __launch_bounds__(256) k_dec(const char* ws, const float* decb, float* out) {
  __shared__ __attribute__((aligned(16))) u16 As[128 * 64];
  __shared__ __attribute__((aligned(16))) u16 Bs[128 * 64];

  const int tid = threadIdx.x, w = tid >> 6, lane = tid & 63;
  const size_t mbase = (size_t)blockIdx.x * 128;
  const size_t nbase = (size_t)blockIdx.y * 128;
  const u16* A = (const u16*)(ws + OFF_HS2) + (size_t)B_ * H_;   // [4096][512] = hs2 slots 1..T
  const u16* Bm = (const u16*)(ws + OFF_DECW);                   // [VPAD][512]

  const int r16 = lane & 15, q8 = (lane >> 4) * 8;
  const int wrow = w >> 1, wcol = w & 1;

  f32x4 zero = {0.f, 0.f, 0.f, 0.f};
  f32x4 acc[4][4];
  #pragma unroll
  for (int mf = 0; mf < 4; ++mf)
    #pragma unroll
    for (int nf = 0; nf < 4; ++nf) acc[mf][nf] = zero;

  for (int ko = 0; ko < 8; ++ko) {
    const int kb = ko * 64;
    #pragma unroll
    for (int i = 0; i < 4; ++i) {
      int row = w * 32 + i * 8 + (lane >> 3);
      int c16 = (lane & 7) * 8;
      const u16* sa = A  + (mbase + row) * 512 + kb + c16;
      const u16* sb = Bm + (nbase + row) * 512 + kb + c16;
      __builtin_amdgcn_global_load_lds((const __attribute__((address_space(1))) void*)sa,
          (__attribute__((address_space(3))) void*)&As[w * 2048 + i * 512], 16, 0, 0);
      __builtin_amdgcn_global_load_lds((const __attribute__((address_space(1))) void*)sb,
          (__attribute__((address_space(3))) void*)&Bs[w * 2048 + i * 512], 16, 0, 0);
    }
    __syncthreads();
    #pragma unroll
    for (int kkh = 0; kkh < 2; ++kkh) {
      const int kk = kkh * 32;
      bf16x8 afr[4], bfr[4];
      #pragma unroll
      for (int x = 0; x < 4; ++x) {
        afr[x] = *(const bf16x8*)&As[(wrow * 64 + x * 16 + r16) * 64 + kk + q8];
        bfr[x] = *(const bf16x8*)&Bs[(wcol * 64 + x * 16 + r16) * 64 + kk + q8];
      }
      #pragma unroll
      for (int mf = 0; mf < 4; ++mf)
        #pragma unroll
        for (int nf = 0; nf < 4; ++nf)
          acc[mf][nf] = __builtin_amdgcn_mfma_f32_16x16x32_bf16(afr[mf], bfr[nf], acc[mf][nf], 0, 0, 0);
    }
    __syncthreads();
  }

  #pragma unroll
  for (int nf = 0; nf < 4; ++nf) {
    int col = (int)nbase + wcol * 64 + nf * 16 + r16;
    if (col < V_) {
      float db = decb[col];
      #pragma unroll
      for (int mf = 0; mf < 4; ++mf) {
        size_t row = mbase + wrow * 64 + mf * 16 + (lane >> 4) * 4;
        #pragma unroll
        for (int r = 0; r < 4; ++r)
          out[(row + r) * (size_t)V_ + col] = acc[mf][nf][r] + db;
      }
    }
  }
}

extern "C" void kernel_launch(void* const* d_in, const int* in_sizes, int n_in,
                              void* d_out, int out_size, void* d_ws, size_t ws_size,
                              hipStream_t stream) {
  const int*   tok  = (const int*)d_in[0];
  const float* h0   = (const float*)d_in[1];
  const float* c0   = (const float*)d_in[2];
  const float* embW = (const float*)d_in[3];
  const float* wih  = (const float*)d_in[4];
  const float* whh  = (const float*)d_in[5];
  const float* bih  = (const float*)d_in[6];
  const float* bhh  = (const float*)d_in[7];
  const float* decw = (const float*)d_in[8];
  const float* decb = (const float*)d_in[9];
  char* ws = (char*)d_ws;
  float* out = (float*)d_out;

  k_prep <<<128,   256, 0, stream>>>(h0, bih, bhh, ws);
  k_embed<<<1024,  256, 0, stream>>>(tok, embW, ws);
  k_wcat <<<2048,  256, 0, stream>>>(wih, whh, ws);
  k_decw <<<12576, 256, 0, stream>>>(decw, ws);
  k_lstm <<<64,    256, 0, stream>>>(c0, ws, out + (size_t)T_ * B_ * V_);
  dim3 gdec(32, 393);
  k_dec  <<<gdec,  256, 0, stream>>>((const char*)ws, decb, out);
}